// Round 10
// baseline (290.375 us; speedup 1.0000x reference)
//
#include <hip/hip_runtime.h>
#include <hip/hip_bf16.h>

#define ENS 7
#define SDIM 30
#define ADIM 8
#define DIN 38          // SDIM + ADIM
#define HID 200
#define DOUT 31         // SDIM + RDIM
#define NHL 3           // hidden layers
#define HS 232          // hA row stride in elems (116 words -> 2-way max on b128 reads)
#define MT 64           // rows per block (4 waves x 16 rows, now fully independent)

typedef __bf16 bf16x8 __attribute__((ext_vector_type(8)));
typedef float f32x4 __attribute__((ext_vector_type(4)));

// ws layout (ushort elems): bf16 weights pre-swizzled into MFMA fragment order.
// Fragment (ct,st) = contiguous 512-ushort (1024 B) block at (ct*S + st)*512;
// element (lane, j) = W[k = st*32 + (lane>>4)*8 + j][n = ct*16 + (lane&15)]  (0 if OOB)
// Consumed as the MFMA A operand (m = out-col).
// R13: every wave consumes ALL cts (no ownership split) for its own 16 rows.
#define U_L1 13312
#define U_H 46592
#define OFF_HD2 (U_L1 + NHL * U_H)            // 153088
#define PER_E (OFF_HD2 + 14336)               // 167424
#define WS_TOTAL (ENS * PER_E)                // 1171968 ushorts = 2.34 MB

__device__ __forceinline__ unsigned short f2bf(float f) {
    unsigned u = __float_as_uint(f);
    u += 0x7fffu + ((u >> 16) & 1u);          // RNE
    return (unsigned short)(u >> 16);
}

__device__ __forceinline__ unsigned pk2(float a, float b) {
    __hip_bfloat162 h = __float22bfloat162_rn(make_float2(a, b));
    return *reinterpret_cast<unsigned*>(&h);
}

__device__ __forceinline__ float softplusf(float x) {
    return fmaxf(x, 0.f) + __logf(1.f + __expf(-fabsf(x)));
}

// ---- prep: fp32 weights -> bf16 fragment-order in ws (layout unchanged since R4) ----
__global__ void prep_kernel(const float* __restrict__ W1, const float* __restrict__ Wh,
                            const float* __restrict__ Wmu, const float* __restrict__ Wsig,
                            unsigned short* __restrict__ ws) {
    int idx = blockIdx.x * 256 + threadIdx.x;
    if (idx >= WS_TOTAL) return;
    int e = idx / PER_E, r = idx % PER_E;
    int j = r & 7, lane = (r >> 3) & 63;
    int l16 = lane & 15, q = lane >> 4;
    float v = 0.f;
    if (r < U_L1) {                            // layer 1 (S=2)
        int fi = r >> 9;
        int ct = fi >> 1, st = fi & 1;
        int k = st * 32 + q * 8 + j, n = ct * 16 + l16;
        if (k < DIN && n < HID) v = W1[(e * DIN + k) * HID + n];
    } else if (r < OFF_HD2) {                  // hidden layers (S=7)
        int rh = r - U_L1;
        int l = rh / U_H, r2 = rh % U_H;
        int fi = r2 >> 9;
        int ct = fi / 7, st = fi % 7;
        int k = st * 32 + q * 8 + j, n = ct * 16 + l16;
        if (k < HID && n < HID) v = Wh[((l * ENS + e) * HID + (long)k) * HID + n];
    } else {                                   // heads (mu cols 0..30, sig cols 32..62)
        int r2 = r - OFF_HD2;
        int fi = r2 >> 9;
        int ct = fi / 7, st = fi % 7;
        int k = st * 32 + q * 8 + j, n = ct * 16 + l16;
        if (k < HID) {
            if (n < DOUT) v = Wmu[(e * HID + k) * DOUT + n];
            else if (n >= 32 && n < 32 + DOUT) v = Wsig[(e * HID + k) * DOUT + (n - 32)];
        }
    }
    ws[idx] = f2bf(v);
}

// R13 layer: one wave computes ALL NCT col-tiles for ITS OWN 16 rows.
// Weights = A operand (SGPR base + lane offset + compile-time frag offsets),
// activations (this wave's rows in LDS) = B operand. One af b128 read per st
// (vs 4 in the R12 structure), NCT weight loads per st.
// Fully self-contained per wave -> NO barriers anywhere.
template<int S, int NCT>
__device__ __forceinline__ void runLayerW(const unsigned short* __restrict__ wbase,
                                          const unsigned short* hrow,
                                          int lo, int quad,
                                          f32x4* acc) {
#pragma unroll
    for (int st = 0; st < S; ++st) {
        bf16x8 af = *((const bf16x8*)(hrow + st * 32 + quad * 8));
        bf16x8 bq[NCT];
#pragma unroll
        for (int ct = 0; ct < NCT; ct++)
            bq[ct] = *((const bf16x8*)(wbase + (ct * S + st) * 512 + lo));
#pragma unroll
        for (int ct = 0; ct < NCT; ct++)
            acc[ct] = __builtin_amdgcn_mfma_f32_16x16x32_bf16(bq[ct], af, acc[ct], 0, 0, 0);
    }
}

// ---- fused 5-layer ensemble MLP ----
// R12 post-mortem: VALU busy-time constant (~79us) across R11->R12; the 13% win was
// reduced serialization -> the remaining ~21% idle is the 10-barrier convoy.
// R13: wave-independent decomposition. Each wave owns 16 rows x all 13 cts; reads
// only its own rows (1 af/st), writes only its own rows. ZERO __syncthreads.
// Trade: 13 weight loads/st (was 4), all L2/L3-hot via e-clustering.
__launch_bounds__(256, 3)
__global__ void ens_mlp_kernel(const float* __restrict__ s, const float* __restrict__ a,
                               const float* __restrict__ b1, const float* __restrict__ bh,
                               const float* __restrict__ bmu, const float* __restrict__ bsig,
                               const float* __restrict__ maxs, const float* __restrict__ mins,
                               const float* __restrict__ maxr, const float* __restrict__ minr,
                               const unsigned short* __restrict__ ws,
                               float* __restrict__ out, int N) {
    __shared__ unsigned short hA[MT * HS];     // 29696 B; 4 disjoint 16-row slices

    const int tid = threadIdx.x;
    const int lane = tid & 63;
    const int quad = lane >> 4, l16 = lane & 15;
    const int swv = __builtin_amdgcn_readfirstlane(tid >> 6);
    const int lo = lane * 8;                   // per-lane weight fragment offset (elems)
    const int bid = blockIdx.x;
    // e-clustering: consecutive blocks share one ensemble's weight stream (FETCH 113->38 MB)
    const int bpe = N / MT;                    // blocks per ensemble (512)
    const int e = bid / bpe, n0 = (bid - e * bpe) * MT;

    const int row = swv * 16 + l16;            // this lane's row within the block tile
    const long g = n0 + row;                   // global batch row
    unsigned short* hrow = hA + row * HS;      // per-lane LDS row base

    // stage own row: x = concat(s,a) as 19 packed bf16 pairs; quad covers idx quad+4i.
    // Also zero K-pad cols [38,64) and [208,232) of own row. Wave-local -> no barrier.
    {
        const float* srow = s + (g * ENS + e) * SDIM;
        const float* arow = a + (g * ENS + e) * ADIM;
#pragma unroll
        for (int i = 0; i < 5; i++) {
            int idx = quad + 4 * i;
            if (idx < 19) {
                float2 p = (idx < 15) ? *((const float2*)(srow + 2 * idx))
                                      : *((const float2*)(arow + 2 * (idx - 15)));
                *((unsigned*)(hrow + 2 * idx)) = pk2(p.x, p.y);
            }
        }
#pragma unroll
        for (int i = 0; i < 4; i++) {
            int k = quad + 4 * i;
            if (k < 13) *((unsigned*)(hrow + 38 + 2 * k)) = 0u;
            if (k < 12) *((unsigned*)(hrow + 208 + 2 * k)) = 0u;
        }
    }

    const unsigned short* we = ws + e * PER_E;

    f32x4 acc[13];      // all 13 col-tiles of this wave's 16 rows

    // acc[ct] = bias (bias-fold, R12). ct12 cols 192..207: quad>=2 is pad -> 0,
    // and pad weights are 0 -> acc stays 0 -> swish writes 0 = next layer's K-pad.
    auto loadBias = [&](const float* bias) {
#pragma unroll
        for (int ct = 0; ct < 12; ct++)
            *((float4*)&acc[ct]) = *((const float4*)(bias + ct * 16 + quad * 4));
        acc[12] = (f32x4){0.f, 0.f, 0.f, 0.f};
        if (quad < 2) *((float4*)&acc[12]) = *((const float4*)(bias + 192 + quad * 4));
    };

    // swish (bias already in acc) -> own row of hA. 13 uint2 stores.
    auto epi = [&]() {
#pragma unroll
        for (int ct = 0; ct < 13; ct++) {
            int col = ct * 16 + quad * 4;
            float v0 = acc[ct][0], v1 = acc[ct][1];
            float v2 = acc[ct][2], v3 = acc[ct][3];
            v0 *= __builtin_amdgcn_rcpf(1.f + __expf(-v0));
            v1 *= __builtin_amdgcn_rcpf(1.f + __expf(-v1));
            v2 *= __builtin_amdgcn_rcpf(1.f + __expf(-v2));
            v3 *= __builtin_amdgcn_rcpf(1.f + __expf(-v3));
            *((uint2*)(hrow + col)) = make_uint2(pk2(v0, v1), pk2(v2, v3));
        }
    };

    // ---- L1 ----
    loadBias(b1 + e * HID);
    runLayerW<2, 13>(we, hrow, lo, quad, acc);
    epi();
    // ---- hidden layers ----
    loadBias(bh + (0 * ENS + e) * HID);
    runLayerW<7, 13>(we + U_L1 + 0 * U_H, hrow, lo, quad, acc);
    epi();
    loadBias(bh + (1 * ENS + e) * HID);
    runLayerW<7, 13>(we + U_L1 + 1 * U_H, hrow, lo, quad, acc);
    epi();
    loadBias(bh + (2 * ENS + e) * HID);
    runLayerW<7, 13>(we + U_L1 + 2 * U_H, hrow, lo, quad, acc);
    epi();

    // ---- head: 4 cts (mu cols 0..31 = ct 0,1 ; sigma cols 32..63 = ct 2,3) ----
    {
#pragma unroll
        for (int ct = 0; ct < 4; ct++) {
            const float* hb = (ct >= 2) ? bsig : bmu;
            f32x4 iH = (f32x4){0.f, 0.f, 0.f, 0.f};
#pragma unroll
            for (int i = 0; i < 4; i++) {
                int c = (ct & 1) * 16 + quad * 4 + i;
                if (c < DOUT) iH[i] = hb[e * DOUT + c];
            }
            acc[ct] = iH;
        }
    }
    runLayerW<7, 4>(we + OFF_HD2, hrow, lo, quad, acc);

    // head tail: lane holds, for each ct, cols (ct&1)*16+quad*4+{0..3} of its row g.
    const long off1 = (long)N * ENS * SDIM;    // ds_sg
    const long off2 = 2 * off1;                // r_mu
    const long off3 = off2 + (long)N * ENS;    // r_sg
    const long rowbase = (g * ENS + e) * SDIM;
#pragma unroll
    for (int ct = 0; ct < 4; ct++) {
        const bool isSig = (ct >= 2);
#pragma unroll
        for (int i = 0; i < 4; i++) {
            int c = (ct & 1) * 16 + quad * 4 + i;
            if (c < DOUT) {
                float v = acc[ct][i];
                if (!isSig) {
                    if (c < SDIM) out[rowbase + c] = v;
                    else out[off2 + g * ENS + e] = v;
                } else {
                    float mx = (c < SDIM) ? maxs[c] : maxr[0];
                    float mn = (c < SDIM) ? mins[c] : minr[0];
                    v = 0.5f * (mx - softplusf(mx - 2.f * v));
                    v = 0.5f * (mn + softplusf(2.f * v - mn));
                    v = __expf(v);
                    if (c < SDIM) out[off1 + rowbase + c] = v;
                    else out[off3 + g * ENS + e] = v;
                }
            }
        }
    }
}

extern "C" void kernel_launch(void* const* d_in, const int* in_sizes, int n_in,
                              void* d_out, int out_size, void* d_ws, size_t ws_size,
                              hipStream_t stream) {
    const float* s    = (const float*)d_in[0];
    const float* a    = (const float*)d_in[1];
    const float* W1   = (const float*)d_in[2];
    const float* b1   = (const float*)d_in[3];
    const float* Wh   = (const float*)d_in[4];
    const float* bh   = (const float*)d_in[5];
    const float* Wmu  = (const float*)d_in[6];
    const float* bmu  = (const float*)d_in[7];
    const float* Wsig = (const float*)d_in[8];
    const float* bsig = (const float*)d_in[9];
    const float* maxs = (const float*)d_in[10];
    const float* mins = (const float*)d_in[11];
    const float* maxr = (const float*)d_in[12];
    const float* minr = (const float*)d_in[13];
    float* out = (float*)d_out;
    unsigned short* ws = (unsigned short*)d_ws;

    int N = in_sizes[0] / (ENS * SDIM);        // 32768

    int prepBlocks = (WS_TOTAL + 255) / 256;
    prep_kernel<<<prepBlocks, 256, 0, stream>>>(W1, Wh, Wmu, Wsig, ws);

    int mainBlocks = (N / MT) * ENS;           // 3584
    ens_mlp_kernel<<<mainBlocks, 256, 0, stream>>>(s, a, b1, bh, bmu, bsig,
                                                   maxs, mins, maxr, minr, ws, out, N);
}

// Round 11
// 258.226 us; speedup vs baseline: 1.1245x; 1.1245x over previous
//
#include <hip/hip_runtime.h>
#include <hip/hip_bf16.h>

#define ENS 7
#define SDIM 30
#define ADIM 8
#define DIN 38          // SDIM + ADIM
#define HID 200
#define DOUT 31         // SDIM + RDIM
#define NHL 3           // hidden layers
#define HS 232          // hA row stride in elems (116 words -> 2-way max on b128 reads)
#define MT 64           // rows per block

typedef __bf16 bf16x8 __attribute__((ext_vector_type(8)));
typedef float f32x4 __attribute__((ext_vector_type(4)));

// ws layout (ushort elems): bf16 weights pre-swizzled into MFMA fragment order.
// Fragment (ct,st) = contiguous 512-ushort (1024 B) block at (ct*S + st)*512;
// element (lane, j) = W[k = st*32 + (lane>>4)*8 + j][n = ct*16 + (lane&15)]  (0 if OOB)
// Consumed as the MFMA A operand (m = out-col). Ownership (NT=13): wave w owns
// cts {3w,3w+1,3w+2} fully + row-slice rt=w of ct 12  -> perfect 13/13/13/13 balance.
#define U_L1 13312
#define U_H 46592
#define OFF_HD2 (U_L1 + NHL * U_H)            // 153088
#define PER_E (OFF_HD2 + 14336)               // 167424
#define WS_TOTAL (ENS * PER_E)                // 1171968 ushorts = 2.34 MB

__device__ __forceinline__ unsigned short f2bf(float f) {
    unsigned u = __float_as_uint(f);
    u += 0x7fffu + ((u >> 16) & 1u);          // RNE
    return (unsigned short)(u >> 16);
}

__device__ __forceinline__ unsigned pk2(float a, float b) {
    __hip_bfloat162 h = __float22bfloat162_rn(make_float2(a, b));
    return *reinterpret_cast<unsigned*>(&h);
}

__device__ __forceinline__ float softplusf(float x) {
    return fmaxf(x, 0.f) + __logf(1.f + __expf(-fabsf(x)));
}

// ---- prep: fp32 weights -> bf16 fragment-order in ws (layout unchanged since R4) ----
__global__ void prep_kernel(const float* __restrict__ W1, const float* __restrict__ Wh,
                            const float* __restrict__ Wmu, const float* __restrict__ Wsig,
                            unsigned short* __restrict__ ws) {
    int idx = blockIdx.x * 256 + threadIdx.x;
    if (idx >= WS_TOTAL) return;
    int e = idx / PER_E, r = idx % PER_E;
    int j = r & 7, lane = (r >> 3) & 63;
    int l16 = lane & 15, q = lane >> 4;
    float v = 0.f;
    if (r < U_L1) {                            // layer 1 (S=2)
        int fi = r >> 9;
        int ct = fi >> 1, st = fi & 1;
        int k = st * 32 + q * 8 + j, n = ct * 16 + l16;
        if (k < DIN && n < HID) v = W1[(e * DIN + k) * HID + n];
    } else if (r < OFF_HD2) {                  // hidden layers (S=7)
        int rh = r - U_L1;
        int l = rh / U_H, r2 = rh % U_H;
        int fi = r2 >> 9;
        int ct = fi / 7, st = fi % 7;
        int k = st * 32 + q * 8 + j, n = ct * 16 + l16;
        if (k < HID && n < HID) v = Wh[((l * ENS + e) * HID + (long)k) * HID + n];
    } else {                                   // heads (mu cols 0..30, sig cols 32..62)
        int r2 = r - OFF_HD2;
        int fi = r2 >> 9;
        int ct = fi / 7, st = fi % 7;
        int k = st * 32 + q * 8 + j, n = ct * 16 + l16;
        if (k < HID) {
            if (n < DOUT) v = Wmu[(e * HID + k) * DOUT + n];
            else if (n >= 32 && n < 32 + DOUT) v = Wsig[(e * HID + k) * DOUT + (n - 32)];
        }
    }
    ws[idx] = f2bf(v);
}

// One layer, balanced ownership (R12 structure, unchanged). Weights = A operand
// (SGPR base + single lane offset), activations (LDS, read buffer) = B operand.
// acc initialized from BIAS (iO/iS); afs read replaced by wave-uniform af[swv] reuse.
// Ping-pong prefetch: cur/nxt roles alternate per st (no reg copies); cross-layer
// st=0 prefetch (NS/NOWN/NSH) issues before the epilogue.
template<int S, int OWN, bool SH, int NS, int NOWN, bool NSH>
__device__ __forceinline__ void runLayer(const unsigned short* __restrict__ fo,
                                         const unsigned short* __restrict__ fs,
                                         const unsigned short* __restrict__ nfo,
                                         const unsigned short* __restrict__ nfs,
                                         const unsigned short* hR,
                                         int lo, int swv, int l16, int quad,
                                         f32x4 (&accO)[4][3], f32x4& accS,
                                         bf16x8 (&bq)[4], bf16x8 (&bt)[4],
                                         const f32x4 (&iO)[3], const f32x4 iS) {
#pragma unroll
    for (int r = 0; r < 4; r++)
#pragma unroll
        for (int c = 0; c < 3; c++) accO[r][c] = iO[c];
    accS = iS;

    auto body = [&](bf16x8 (&cur)[4], bf16x8 (&nxt)[4], int st) {
        if (st + 1 < S) {
#pragma unroll
            for (int c = 0; c < OWN; c++) nxt[c] = *((const bf16x8*)(fo + (c * S + st + 1) * 512 + lo));
            if (SH) nxt[3] = *((const bf16x8*)(fs + (st + 1) * 512 + lo));
        } else if (NS > 0) {
#pragma unroll
            for (int c = 0; c < NOWN; c++) nxt[c] = *((const bf16x8*)(nfo + (c * NS) * 512 + lo));
            if (NSH) nxt[3] = *((const bf16x8*)(nfs + lo));
        }
        bf16x8 af[4];
#pragma unroll
        for (int r = 0; r < 4; r++)
            af[r] = *((const bf16x8*)(hR + (r * 16 + l16) * HS + st * 32 + quad * 8));
#pragma unroll
        for (int c = 0; c < OWN; c++)
#pragma unroll
            for (int r = 0; r < 4; r++)
                accO[r][c] = __builtin_amdgcn_mfma_f32_16x16x32_bf16(cur[c], af[r], accO[r][c], 0, 0, 0);
        if (SH) {
#pragma unroll
            for (int r = 0; r < 4; r++)
                if (swv == r)   // wave-uniform scalar branch; af[swv] == old afs data
                    accS = __builtin_amdgcn_mfma_f32_16x16x32_bf16(cur[3], af[r], accS, 0, 0, 0);
        }
    };

#pragma unroll
    for (int st = 0; st < S; ++st) {
        if ((st & 1) == 0) body(bq, bt, st);
        else               body(bt, bq, st);
    }
}

// ---- fused 5-layer ensemble MLP ----
// R13 post-mortem: barrier-free wave-independent split quadrupled weight traffic
// (~22 TB/s L2) and lost prefetch -> 210us. Weight reuse across 64 rows REQUIRES
// cross-wave sharing, hence sync. R14: keep R12's sharing, DOUBLE-BUFFER hA so the
// epilogue writes the other buffer: WAR pre-epi barrier deleted -> 1 barrier/layer
// (5 total, was 10); GEMM+epi phase is wave-private. LDS 59.4KB -> 2 blocks/CU.
__launch_bounds__(256, 2)
__global__ void ens_mlp_kernel(const float* __restrict__ s, const float* __restrict__ a,
                               const float* __restrict__ b1, const float* __restrict__ bh,
                               const float* __restrict__ bmu, const float* __restrict__ bsig,
                               const float* __restrict__ maxs, const float* __restrict__ mins,
                               const float* __restrict__ maxr, const float* __restrict__ minr,
                               const unsigned short* __restrict__ ws,
                               float* __restrict__ out, int N) {
    __shared__ unsigned short hA[2][MT * HS];  // 59392 B double buffer

    const int tid = threadIdx.x;
    const int wv = tid >> 6, lane = tid & 63;
    const int quad = lane >> 4, l16 = lane & 15;
    const int swv = __builtin_amdgcn_readfirstlane(wv);   // wave-uniform -> SGPR addressing
    const int lo = lane * 8;                   // single per-lane weight offset (elems)
    const int bid = blockIdx.x;
    // e-clustering: consecutive blocks share one ensemble's weight stream (FETCH 113->38 MB)
    const int bpe = N / MT;                    // blocks per ensemble (512)
    const int e = bid / bpe, n0 = (bid - e * bpe) * MT;

    // zero K-pad cols: [38,64) in buf0 (L1 reads it); [208,232) in BOTH buffers
    // (hidden/head GEMMs read st<=6 -> cols up to 224; epi never writes >=208).
    for (int t = tid; t < MT * 13; t += 256) {
        int row = t / 13, k = t - row * 13;
        *((unsigned*)(hA[0] + row * HS + 38 + 2 * k)) = 0u;
    }
    for (int t = tid; t < MT * 12; t += 256) {
        int row = t / 12, k = t - row * 12;
        *((unsigned*)(hA[0] + row * HS + 208 + 2 * k)) = 0u;
        *((unsigned*)(hA[1] + row * HS + 208 + 2 * k)) = 0u;
    }

    // stage x = concat(s, a) -> buf0 cols 0..37 as 19 packed bf16 pairs per row.
    {
        int m = tid & 63, cg = tid >> 6;
        long g = n0 + m;
        const float* srow = s + (g * ENS + e) * SDIM;
        const float* arow = a + (g * ENS + e) * ADIM;
#pragma unroll
        for (int k = 0; k < 5; k++) {
            int idx = cg * 5 + k;
            if (idx < 19) {
                float2 p = (idx < 15) ? *((const float2*)(srow + 2 * idx))
                                      : *((const float2*)(arow + 2 * (idx - 15)));
                *((unsigned*)(hA[0] + m * HS + 2 * idx)) = pk2(p.x, p.y);
            }
        }
    }
    __syncthreads();   // staging + pad zeroing visible to all waves

    // wave-uniform fragment base pointers (SGPR; per-lane part is `lo`)
    const unsigned short* we = ws + e * PER_E;
    const unsigned short* L1o = we + swv * 3 * 2 * 512;
    const unsigned short* L1s = we + 12 * 2 * 512;
    const unsigned short* H0o = we + U_L1 + swv * 3 * 7 * 512;
    const unsigned short* H0s = we + U_L1 + 12 * 7 * 512;
    const unsigned short* H1o = H0o + U_H;
    const unsigned short* H1s = H0s + U_H;
    const unsigned short* H2o = H1o + U_H;
    const unsigned short* H2s = H1s + U_H;
    const unsigned short* HDo = we + OFF_HD2 + swv * 7 * 512;

    f32x4 accO[4][3];   // own col-tiles: [row-tile][c]
    f32x4 accS;         // shared ct12, row-tile = swv
    bf16x8 bqA[4], bqB[4];   // ping-pong weight fragment buffers
    f32x4 iO[3];        // bias-init for own col-tiles
    f32x4 iS;           // bias-init for shared ct12 (cols >= HID -> 0 keeps K-pad)

    auto loadBias = [&](const float* bias) {
#pragma unroll
        for (int c = 0; c < 3; c++)
            *((float4*)&iO[c]) = *((const float4*)(bias + (3 * swv + c) * 16 + quad * 4));
        int col = 192 + quad * 4;
        iS = (f32x4){0.f, 0.f, 0.f, 0.f};
        if (col < HID) *((float4*)&iS) = *((const float4*)(bias + col));   // quad 0,1 only
    };

    // swish (bias already in acc) -> WRITE buffer hW (the other buffer).
    auto epiH = [&](unsigned short* hW) {
#pragma unroll
        for (int c = 0; c < 3; c++) {
            int col = (3 * swv + c) * 16 + quad * 4;
#pragma unroll
            for (int r = 0; r < 4; r++) {
                float v0 = accO[r][c][0], v1 = accO[r][c][1];
                float v2 = accO[r][c][2], v3 = accO[r][c][3];
                v0 *= __builtin_amdgcn_rcpf(1.f + __expf(-v0));
                v1 *= __builtin_amdgcn_rcpf(1.f + __expf(-v1));
                v2 *= __builtin_amdgcn_rcpf(1.f + __expf(-v2));
                v3 *= __builtin_amdgcn_rcpf(1.f + __expf(-v3));
                *((uint2*)(hW + (r * 16 + l16) * HS + col)) = make_uint2(pk2(v0, v1), pk2(v2, v3));
            }
        }
        {
            int col = 192 + quad * 4;
            float v0 = accS[0], v1 = accS[1], v2 = accS[2], v3 = accS[3];
            v0 *= __builtin_amdgcn_rcpf(1.f + __expf(-v0));
            v1 *= __builtin_amdgcn_rcpf(1.f + __expf(-v1));
            v2 *= __builtin_amdgcn_rcpf(1.f + __expf(-v2));
            v3 *= __builtin_amdgcn_rcpf(1.f + __expf(-v3));
            *((uint2*)(hW + (swv * 16 + l16) * HS + col)) = make_uint2(pk2(v0, v1), pk2(v2, v3));
        }
    };

    // initial fragment load (L1, st=0) -> bqA ; L1 bias -> iO/iS
    loadBias(b1 + e * HID);
#pragma unroll
    for (int c = 0; c < 3; c++) bqA[c] = *((const bf16x8*)(L1o + (c * 2) * 512 + lo));
    bqA[3] = *((const bf16x8*)(L1s + lo));

    // Layer chain. Read/write buffers alternate; ONE barrier per layer (post-epi RAW).
    // L1: read buf0, write buf1
    runLayer<2, 3, true, 7, 3, true>(L1o, L1s, H0o, H0s, hA[0], lo, swv, l16, quad, accO, accS, bqA, bqB, iO, iS);
    loadBias(bh + (0 * ENS + e) * HID);
    epiH(hA[1]);
    __syncthreads();
    // H0: read buf1, write buf0
    runLayer<7, 3, true, 7, 3, true>(H0o, H0s, H1o, H1s, hA[1], lo, swv, l16, quad, accO, accS, bqA, bqB, iO, iS);
    loadBias(bh + (1 * ENS + e) * HID);
    epiH(hA[0]);
    __syncthreads();
    // H1: read buf0, write buf1
    runLayer<7, 3, true, 7, 3, true>(H1o, H1s, H2o, H2s, hA[0], lo, swv, l16, quad, accO, accS, bqB, bqA, iO, iS);
    loadBias(bh + (2 * ENS + e) * HID);
    epiH(hA[1]);
    __syncthreads();
    // H2: read buf1, write buf0
    runLayer<7, 3, true, 7, 1, false>(H2o, H2s, HDo, (const unsigned short*)nullptr,
                                      hA[1], lo, swv, l16, quad, accO, accS, bqA, bqB, iO, iS);

    // head bias + sigma clamp params (loaded before the last epilogue; latency hidden)
    const bool isSig = (swv >= 2);
    const int c0 = (swv & 1) * 16 + quad * 4;
    {
        f32x4 iH = (f32x4){0.f, 0.f, 0.f, 0.f};
        const float* hb = isSig ? bsig : bmu;
#pragma unroll
        for (int i = 0; i < 4; i++)
            if (c0 + i < DOUT) iH[i] = hb[e * DOUT + c0 + i];
        iO[0] = iH;
        iO[1] = (f32x4){0.f, 0.f, 0.f, 0.f};
        iO[2] = (f32x4){0.f, 0.f, 0.f, 0.f};
        iS = (f32x4){0.f, 0.f, 0.f, 0.f};
    }
    float mx_i[4], mn_i[4];
#pragma unroll
    for (int i = 0; i < 4; i++) {
        int c = c0 + i;
        if (isSig) {
            mx_i[i] = (c < SDIM) ? maxs[c] : maxr[0];
            mn_i[i] = (c < SDIM) ? mins[c] : minr[0];
        } else { mx_i[i] = 0.f; mn_i[i] = 0.f; }
    }
    epiH(hA[0]);   // bh2 epilogue -> buf0
    __syncthreads();
    // head: read buf0
    runLayer<7, 1, false, 0, 0, false>(HDo, (const unsigned short*)nullptr,
                                       (const unsigned short*)nullptr, (const unsigned short*)nullptr,
                                       hA[0], lo, swv, l16, quad, accO, accS, bqB, bqA, iO, iS);
    // no barrier: head tail reads only registers, writes only global

    // head tail: wave owns ct = swv -> lane holds cols swv*16+quad*4+{0..3}
    // (mu block 0..31 for swv<2, sigma block 32..63 for swv>=2), rows r*16+l16.
    const long off1 = (long)N * ENS * SDIM;    // ds_sg
    const long off2 = 2 * off1;                // r_mu
    const long off3 = off2 + (long)N * ENS;    // r_sg
#pragma unroll
    for (int r = 0; r < 4; r++) {
        long g = n0 + r * 16 + l16;
        long rowbase = (g * ENS + e) * SDIM;
#pragma unroll
        for (int i = 0; i < 4; i++) {
            int c = c0 + i;
            if (c < DOUT) {
                float v = accO[r][0][i];
                if (!isSig) {
                    if (c < SDIM) out[rowbase + c] = v;
                    else out[off2 + g * ENS + e] = v;
                } else {
                    v = 0.5f * (mx_i[i] - softplusf(mx_i[i] - 2.f * v));
                    v = 0.5f * (mn_i[i] + softplusf(2.f * v - mn_i[i]));
                    v = __expf(v);
                    if (c < SDIM) out[off1 + rowbase + c] = v;
                    else out[off3 + g * ENS + e] = v;
                }
            }
        }
    }
}

extern "C" void kernel_launch(void* const* d_in, const int* in_sizes, int n_in,
                              void* d_out, int out_size, void* d_ws, size_t ws_size,
                              hipStream_t stream) {
    const float* s    = (const float*)d_in[0];
    const float* a    = (const float*)d_in[1];
    const float* W1   = (const float*)d_in[2];
    const float* b1   = (const float*)d_in[3];
    const float* Wh   = (const float*)d_in[4];
    const float* bh   = (const float*)d_in[5];
    const float* Wmu  = (const float*)d_in[6];
    const float* bmu  = (const float*)d_in[7];
    const float* Wsig = (const float*)d_in[8];
    const float* bsig = (const float*)d_in[9];
    const float* maxs = (const float*)d_in[10];
    const float* mins = (const float*)d_in[11];
    const float* maxr = (const float*)d_in[12];
    const float* minr = (const float*)d_in[13];
    float* out = (float*)d_out;
    unsigned short* ws = (unsigned short*)d_ws;

    int N = in_sizes[0] / (ENS * SDIM);        // 32768

    int prepBlocks = (WS_TOTAL + 255) / 256;
    prep_kernel<<<prepBlocks, 256, 0, stream>>>(W1, Wh, Wmu, Wsig, ws);

    int mainBlocks = (N / MT) * ENS;           // 3584
    ens_mlp_kernel<<<mainBlocks, 256, 0, stream>>>(s, a, b1, bh, bmu, bsig,
                                                   maxs, mins, maxr, minr, ws, out, N);
}

// Round 13
// 230.587 us; speedup vs baseline: 1.2593x; 1.1199x over previous
//
#include <hip/hip_runtime.h>
#include <hip/hip_bf16.h>

#define ENS 7
#define SDIM 30
#define ADIM 8
#define DIN 38          // SDIM + ADIM
#define HID 200
#define DOUT 31         // SDIM + RDIM
#define NHL 3           // hidden layers
#define HS 232          // hA row stride in elems (116 words -> 2-way max on b128 reads)
#define MT 64           // rows per block

typedef __bf16 bf16x8 __attribute__((ext_vector_type(8)));
typedef float f32x4 __attribute__((ext_vector_type(4)));

// ws layout (ushort elems): bf16 weights pre-swizzled into MFMA fragment order.
// Fragment (ct,st) = contiguous 512-ushort (1024 B) block at (ct*S + st)*512;
// element (lane, j) = W[k = st*32 + (lane>>4)*8 + j][n = ct*16 + (lane&15)]  (0 if OOB)
// Consumed as the MFMA A operand (m = out-col). Ownership (NT=13): wave w owns
// cts {3w,3w+1,3w+2} fully + row-slice rt=w of ct 12  -> perfect 13/13/13/13 balance.
#define U_L1 13312
#define U_H 46592
#define OFF_HD2 (U_L1 + NHL * U_H)            // 153088
#define PER_E (OFF_HD2 + 14336)               // 167424
#define WS_TOTAL (ENS * PER_E)                // 1171968 ushorts = 2.34 MB

__device__ __forceinline__ unsigned short f2bf(float f) {
    unsigned u = __float_as_uint(f);
    u += 0x7fffu + ((u >> 16) & 1u);          // RNE
    return (unsigned short)(u >> 16);
}

__device__ __forceinline__ unsigned pk2(float a, float b) {
    __hip_bfloat162 h = __float22bfloat162_rn(make_float2(a, b));
    return *reinterpret_cast<unsigned*>(&h);
}

__device__ __forceinline__ float softplusf(float x) {
    return fmaxf(x, 0.f) + __logf(1.f + __expf(-fabsf(x)));
}

// ---- prep: fp32 weights -> bf16 fragment-order in ws (layout unchanged since R4) ----
__global__ void prep_kernel(const float* __restrict__ W1, const float* __restrict__ Wh,
                            const float* __restrict__ Wmu, const float* __restrict__ Wsig,
                            unsigned short* __restrict__ ws) {
    int idx = blockIdx.x * 256 + threadIdx.x;
    if (idx >= WS_TOTAL) return;
    int e = idx / PER_E, r = idx % PER_E;
    int j = r & 7, lane = (r >> 3) & 63;
    int l16 = lane & 15, q = lane >> 4;
    float v = 0.f;
    if (r < U_L1) {                            // layer 1 (S=2)
        int fi = r >> 9;
        int ct = fi >> 1, st = fi & 1;
        int k = st * 32 + q * 8 + j, n = ct * 16 + l16;
        if (k < DIN && n < HID) v = W1[(e * DIN + k) * HID + n];
    } else if (r < OFF_HD2) {                  // hidden layers (S=7)
        int rh = r - U_L1;
        int l = rh / U_H, r2 = rh % U_H;
        int fi = r2 >> 9;
        int ct = fi / 7, st = fi % 7;
        int k = st * 32 + q * 8 + j, n = ct * 16 + l16;
        if (k < HID && n < HID) v = Wh[((l * ENS + e) * HID + (long)k) * HID + n];
    } else {                                   // heads (mu cols 0..30, sig cols 32..62)
        int r2 = r - OFF_HD2;
        int fi = r2 >> 9;
        int ct = fi / 7, st = fi % 7;
        int k = st * 32 + q * 8 + j, n = ct * 16 + l16;
        if (k < HID) {
            if (n < DOUT) v = Wmu[(e * HID + k) * DOUT + n];
            else if (n >= 32 && n < 32 + DOUT) v = Wsig[(e * HID + k) * DOUT + (n - 32)];
        }
    }
    ws[idx] = f2bf(v);
}

// One layer, balanced ownership (R12 structure, unchanged). Weights = A operand
// (SGPR base + single lane offset), activations (LDS) = B operand.
// acc initialized from BIAS (iO/iS); afs read replaced by wave-uniform af[swv] reuse.
// Ping-pong prefetch: cur/nxt roles alternate per st (no reg copies); cross-layer
// st=0 prefetch (NS/NOWN/NSH) issues before the epilogue barriers.
template<int S, int OWN, bool SH, int NS, int NOWN, bool NSH>
__device__ __forceinline__ void runLayer(const unsigned short* __restrict__ fo,
                                         const unsigned short* __restrict__ fs,
                                         const unsigned short* __restrict__ nfo,
                                         const unsigned short* __restrict__ nfs,
                                         const unsigned short* hA,
                                         int lo, int swv, int l16, int quad,
                                         f32x4 (&accO)[4][3], f32x4& accS,
                                         bf16x8 (&bq)[4], bf16x8 (&bt)[4],
                                         const f32x4 (&iO)[3], const f32x4 iS) {
#pragma unroll
    for (int r = 0; r < 4; r++)
#pragma unroll
        for (int c = 0; c < 3; c++) accO[r][c] = iO[c];
    accS = iS;

    auto body = [&](bf16x8 (&cur)[4], bf16x8 (&nxt)[4], int st) {
        if (st + 1 < S) {
#pragma unroll
            for (int c = 0; c < OWN; c++) nxt[c] = *((const bf16x8*)(fo + (c * S + st + 1) * 512 + lo));
            if (SH) nxt[3] = *((const bf16x8*)(fs + (st + 1) * 512 + lo));
        } else if (NS > 0) {
#pragma unroll
            for (int c = 0; c < NOWN; c++) nxt[c] = *((const bf16x8*)(nfo + (c * NS) * 512 + lo));
            if (NSH) nxt[3] = *((const bf16x8*)(nfs + lo));
        }
        bf16x8 af[4];
#pragma unroll
        for (int r = 0; r < 4; r++)
            af[r] = *((const bf16x8*)(hA + (r * 16 + l16) * HS + st * 32 + quad * 8));
#pragma unroll
        for (int c = 0; c < OWN; c++)
#pragma unroll
            for (int r = 0; r < 4; r++)
                accO[r][c] = __builtin_amdgcn_mfma_f32_16x16x32_bf16(cur[c], af[r], accO[r][c], 0, 0, 0);
        if (SH) {
#pragma unroll
            for (int r = 0; r < 4; r++)
                if (swv == r)   // wave-uniform scalar branch; af[swv] == old afs data
                    accS = __builtin_amdgcn_mfma_f32_16x16x32_bf16(cur[3], af[r], accS, 0, 0, 0);
        }
    };

#pragma unroll
    for (int st = 0; st < S; ++st) {
        if ((st & 1) == 0) body(bq, bt, st);
        else               body(bt, bq, st);
    }
}

// ---- fused 5-layer ensemble MLP ----
// R14 post-mortem: double-buffer (5 barriers, 2 blocks/CU @21%) = 177us -> occupancy
// below ~30% hurts; barriers were NOT the R12 idle. R15 = R12 VERBATIM except
// __launch_bounds__(256,4): R12's diet cut live regs to ~116 (64 arch + 52 acc)
// which fits the 128-reg budget of 4 waves/SIMD -- the one untested occupancy step.
// Tripwire: WRITE_SIZE > 95 MB = spill -> revert to (256,3).
__launch_bounds__(256, 4)
__global__ void ens_mlp_kernel(const float* __restrict__ s, const float* __restrict__ a,
                               const float* __restrict__ b1, const float* __restrict__ bh,
                               const float* __restrict__ bmu, const float* __restrict__ bsig,
                               const float* __restrict__ maxs, const float* __restrict__ mins,
                               const float* __restrict__ maxr, const float* __restrict__ minr,
                               const unsigned short* __restrict__ ws,
                               float* __restrict__ out, int N) {
    __shared__ unsigned short hA[MT * HS];     // 29696 B, activations (bf16) -- only LDS

    const int tid = threadIdx.x;
    const int wv = tid >> 6, lane = tid & 63;
    const int quad = lane >> 4, l16 = lane & 15;
    const int swv = __builtin_amdgcn_readfirstlane(wv);   // wave-uniform -> SGPR addressing
    const int lo = lane * 8;                   // single per-lane weight offset (elems)
    const int bid = blockIdx.x;
    // e-clustering: consecutive blocks share one ensemble's weight stream (proven
    // FETCH 113->38 MB).
    const int bpe = N / MT;                    // blocks per ensemble (512)
    const int e = bid / bpe, n0 = (bid - e * bpe) * MT;

    // zero ONLY the K-pad cols: [38,64) and [208,232). All other cols are written
    // (staged or epilogue) before any read. Pad cols survive all layers untouched.
    for (int t = tid; t < MT * 13; t += 256) {
        int row = t / 13, k = t - row * 13;
        *((unsigned*)(hA + row * HS + 38 + 2 * k)) = 0u;
    }
    for (int t = tid; t < MT * 12; t += 256) {
        int row = t / 12, k = t - row * 12;
        *((unsigned*)(hA + row * HS + 208 + 2 * k)) = 0u;
    }

    // stage x = concat(s, a) -> hA cols 0..37 as 19 packed bf16 pairs per row.
    // float2 load + pk2 + u32 store (5 instrs/thread vs 30 scalar).
    {
        int m = tid & 63, cg = tid >> 6;
        long g = n0 + m;
        const float* srow = s + (g * ENS + e) * SDIM;
        const float* arow = a + (g * ENS + e) * ADIM;
#pragma unroll
        for (int k = 0; k < 5; k++) {
            int idx = cg * 5 + k;
            if (idx < 19) {
                float2 p = (idx < 15) ? *((const float2*)(srow + 2 * idx))
                                      : *((const float2*)(arow + 2 * (idx - 15)));
                *((unsigned*)(hA + m * HS + 2 * idx)) = pk2(p.x, p.y);
            }
        }
    }
    __syncthreads();

    // wave-uniform fragment base pointers (SGPR; per-lane part is `lo`)
    const unsigned short* we = ws + e * PER_E;
    const unsigned short* L1o = we + swv * 3 * 2 * 512;
    const unsigned short* L1s = we + 12 * 2 * 512;
    const unsigned short* H0o = we + U_L1 + swv * 3 * 7 * 512;
    const unsigned short* H0s = we + U_L1 + 12 * 7 * 512;
    const unsigned short* H1o = H0o + U_H;
    const unsigned short* H1s = H0s + U_H;
    const unsigned short* H2o = H1o + U_H;
    const unsigned short* H2s = H1s + U_H;
    const unsigned short* HDo = we + OFF_HD2 + swv * 7 * 512;

    f32x4 accO[4][3];   // own col-tiles: [row-tile][c]
    f32x4 accS;         // shared ct12, row-tile = swv
    bf16x8 bqA[4], bqB[4];   // ping-pong weight fragment buffers
    f32x4 iO[3];        // bias-init for own col-tiles (col-dependent only, same all r)
    f32x4 iS;           // bias-init for shared ct12 (cols >= HID -> 0 keeps K-pad)

    // load the CURRENT layer's bias into iO/iS; issued before the preceding epilogue
    // so L2 latency hides under ~1000 cyc of swish VALU.
    auto loadBias = [&](const float* bias) {
#pragma unroll
        for (int c = 0; c < 3; c++)
            *((float4*)&iO[c]) = *((const float4*)(bias + (3 * swv + c) * 16 + quad * 4));
        int col = 192 + quad * 4;
        iS = (f32x4){0.f, 0.f, 0.f, 0.f};
        if (col < HID) *((float4*)&iS) = *((const float4*)(bias + col));   // quad 0,1 only
    };

    // swish (bias already in acc) -> hA. Own cts: col < 192 always.
    // Shared ct12: cols 192..207; pad cols (>=200) had zero weights+bias -> writes 0.
    auto epiH = [&]() {
#pragma unroll
        for (int c = 0; c < 3; c++) {
            int col = (3 * swv + c) * 16 + quad * 4;
#pragma unroll
            for (int r = 0; r < 4; r++) {
                float v0 = accO[r][c][0], v1 = accO[r][c][1];
                float v2 = accO[r][c][2], v3 = accO[r][c][3];
                v0 *= __builtin_amdgcn_rcpf(1.f + __expf(-v0));
                v1 *= __builtin_amdgcn_rcpf(1.f + __expf(-v1));
                v2 *= __builtin_amdgcn_rcpf(1.f + __expf(-v2));
                v3 *= __builtin_amdgcn_rcpf(1.f + __expf(-v3));
                *((uint2*)(hA + (r * 16 + l16) * HS + col)) = make_uint2(pk2(v0, v1), pk2(v2, v3));
            }
        }
        {
            int col = 192 + quad * 4;
            float v0 = accS[0], v1 = accS[1], v2 = accS[2], v3 = accS[3];
            v0 *= __builtin_amdgcn_rcpf(1.f + __expf(-v0));
            v1 *= __builtin_amdgcn_rcpf(1.f + __expf(-v1));
            v2 *= __builtin_amdgcn_rcpf(1.f + __expf(-v2));
            v3 *= __builtin_amdgcn_rcpf(1.f + __expf(-v3));
            *((uint2*)(hA + (swv * 16 + l16) * HS + col)) = make_uint2(pk2(v0, v1), pk2(v2, v3));
        }
    };

    // initial fragment load (L1, st=0) -> bqA ; L1 bias -> iO/iS
    loadBias(b1 + e * HID);
#pragma unroll
    for (int c = 0; c < 3; c++) bqA[c] = *((const bf16x8*)(L1o + (c * 2) * 512 + lo));
    bqA[3] = *((const bf16x8*)(L1s + lo));

    // Buffer parity chain: L1(S=2) in A out A; each S=7 layer flips.
    runLayer<2, 3, true, 7, 3, true>(L1o, L1s, H0o, H0s, hA, lo, swv, l16, quad, accO, accS, bqA, bqB, iO, iS);
    __syncthreads();
    loadBias(bh + (0 * ENS + e) * HID);
    epiH();
    __syncthreads();
    runLayer<7, 3, true, 7, 3, true>(H0o, H0s, H1o, H1s, hA, lo, swv, l16, quad, accO, accS, bqA, bqB, iO, iS);
    __syncthreads();
    loadBias(bh + (1 * ENS + e) * HID);
    epiH();
    __syncthreads();
    runLayer<7, 3, true, 7, 3, true>(H1o, H1s, H2o, H2s, hA, lo, swv, l16, quad, accO, accS, bqB, bqA, iO, iS);
    __syncthreads();
    loadBias(bh + (2 * ENS + e) * HID);
    epiH();
    __syncthreads();
    runLayer<7, 3, true, 7, 1, false>(H2o, H2s, HDo, (const unsigned short*)nullptr,
                                      hA, lo, swv, l16, quad, accO, accS, bqA, bqB, iO, iS);
    __syncthreads();

    // head bias + sigma clamp params, loaded before the last epilogue (latency hidden)
    const bool isSig = (swv >= 2);
    const int c0 = (swv & 1) * 16 + quad * 4;
    {
        f32x4 iH = (f32x4){0.f, 0.f, 0.f, 0.f};
        const float* hb = isSig ? bsig : bmu;
#pragma unroll
        for (int i = 0; i < 4; i++)
            if (c0 + i < DOUT) iH[i] = hb[e * DOUT + c0 + i];
        iO[0] = iH;
        iO[1] = (f32x4){0.f, 0.f, 0.f, 0.f};
        iO[2] = (f32x4){0.f, 0.f, 0.f, 0.f};
        iS = (f32x4){0.f, 0.f, 0.f, 0.f};
    }
    float mx_i[4], mn_i[4];
#pragma unroll
    for (int i = 0; i < 4; i++) {
        int c = c0 + i;
        if (isSig) {
            mx_i[i] = (c < SDIM) ? maxs[c] : maxr[0];
            mn_i[i] = (c < SDIM) ? mins[c] : minr[0];
        } else { mx_i[i] = 0.f; mn_i[i] = 0.f; }
    }
    epiH();   // bh2 epilogue
    __syncthreads();
    runLayer<7, 1, false, 0, 0, false>(HDo, (const unsigned short*)nullptr,
                                       (const unsigned short*)nullptr, (const unsigned short*)nullptr,
                                       hA, lo, swv, l16, quad, accO, accS, bqB, bqA, iO, iS);
    // no barrier: head tail reads only registers, writes only global

    // head tail: wave owns ct = swv -> lane holds cols swv*16+quad*4+{0..3}
    // (mu block 0..31 for swv<2, sigma block 32..63 for swv>=2), rows r*16+l16.
    // Bias already folded into acc init.
    const long off1 = (long)N * ENS * SDIM;    // ds_sg
    const long off2 = 2 * off1;                // r_mu
    const long off3 = off2 + (long)N * ENS;    // r_sg
#pragma unroll
    for (int r = 0; r < 4; r++) {
        long g = n0 + r * 16 + l16;
        long rowbase = (g * ENS + e) * SDIM;
#pragma unroll
        for (int i = 0; i < 4; i++) {
            int c = c0 + i;
            if (c < DOUT) {
                float v = accO[r][0][i];
                if (!isSig) {
                    if (c < SDIM) out[rowbase + c] = v;
                    else out[off2 + g * ENS + e] = v;
                } else {
                    v = 0.5f * (mx_i[i] - softplusf(mx_i[i] - 2.f * v));
                    v = 0.5f * (mn_i[i] + softplusf(2.f * v - mn_i[i]));
                    v = __expf(v);
                    if (c < SDIM) out[off1 + rowbase + c] = v;
                    else out[off3 + g * ENS + e] = v;
                }
            }
        }
    }
}

extern "C" void kernel_launch(void* const* d_in, const int* in_sizes, int n_in,
                              void* d_out, int out_size, void* d_ws, size_t ws_size,
                              hipStream_t stream) {
    const float* s    = (const float*)d_in[0];
    const float* a    = (const float*)d_in[1];
    const float* W1   = (const float*)d_in[2];
    const float* b1   = (const float*)d_in[3];
    const float* Wh   = (const float*)d_in[4];
    const float* bh   = (const float*)d_in[5];
    const float* Wmu  = (const float*)d_in[6];
    const float* bmu  = (const float*)d_in[7];
    const float* Wsig = (const float*)d_in[8];
    const float* bsig = (const float*)d_in[9];
    const float* maxs = (const float*)d_in[10];
    const float* mins = (const float*)d_in[11];
    const float* maxr = (const float*)d_in[12];
    const float* minr = (const float*)d_in[13];
    float* out = (float*)d_out;
    unsigned short* ws = (unsigned short*)d_ws;

    int N = in_sizes[0] / (ENS * SDIM);        // 32768

    int prepBlocks = (WS_TOTAL + 255) / 256;
    prep_kernel<<<prepBlocks, 256, 0, stream>>>(W1, Wh, Wmu, Wsig, ws);

    int mainBlocks = (N / MT) * ENS;           // 3584
    ens_mlp_kernel<<<mainBlocks, 256, 0, stream>>>(s, a, b1, bh, bmu, bsig,
                                                   maxs, mins, maxr, minr, ws, out, N);
}